// Round 9
// baseline (1323.963 us; speedup 1.0000x reference)
//
#include <hip/hip_runtime.h>
#include <hip/hip_cooperative_groups.h>

namespace cg = cooperative_groups;

// Problem constants: G=256, B=4 -> input key space 2^26 (8 MB bitmap).
// Parent/ref coords are even -> compressed key (b,x/2,y/2,z/2) in 2^23 (1 MB bitmap).
// Monotone bijection => same sorted-unique order as the reference.
#define WORDS_IN (1u << 21)   // 2^26 / 32
#define WORDS_P  (1u << 18)   // 2^23 / 32
#define NBLK     2048

__device__ __forceinline__ unsigned key_of(int b, int x, int y, int z) {
  return ((unsigned)b << 24) | ((unsigned)x << 16) | ((unsigned)y << 8) | (unsigned)z;
}

__global__ __launch_bounds__(256, 8) void mega(const float* __restrict__ feats,
                                               const float* __restrict__ Wg,
                                               const float* __restrict__ bias,
                                               const int4* __restrict__ coords,
                                               const int4* __restrict__ ref,
                                               int N, int NREF,
                                               float* __restrict__ outbuf,
                                               char* __restrict__ ws) {
  // workspace layout
  unsigned* inbm    = (unsigned*)(ws);                    // 8 MB
  unsigned* inpre   = (unsigned*)(ws + (8u << 20));       // 8 MB
  unsigned* parbm   = (unsigned*)(ws + (16u << 20));      // 1 MB
  unsigned* refbm   = (unsigned*)(ws + (17u << 20));      // 1 MB (becomes maskbm)
  unsigned* parpre  = (unsigned*)(ws + (18u << 20));      // 1 MB
  unsigned* maskpre = (unsigned*)(ws + (19u << 20));      // 1 MB
  unsigned* srow    = (unsigned*)(ws + (20u << 20));      // 4 MB
  uint2*    mlist   = (uint2*)   (ws + (24u << 20));      // 8 MB
  unsigned* bsums   = (unsigned*)(ws + (32u << 20));            // 3*2048 u32
  unsigned* bscan   = (unsigned*)(ws + (32u << 20) + 32768);    // 3*2048 u32
  unsigned* counter = (unsigned*)(ws + (32u << 20) + 65536);    // 1 u32

  float4* out_coords = (float4*)outbuf;
  float*  out_feats  = outbuf + (size_t)N * 4u;
  float*  out_mask   = outbuf + (size_t)N * 68u;

  cg::grid_group grid = cg::this_grid();
  __shared__ unsigned s[256];
  unsigned t = threadIdx.x;
  unsigned tid = blockIdx.x * 256u + t;
  unsigned nthr = gridDim.x * 256u;

  // ---- P0: fills (bitmaps=0, feats+mask=0, coords=-1) ----
  {
    float4 z = make_float4(0.f, 0.f, 0.f, 0.f);
    float4 m1 = make_float4(-1.f, -1.f, -1.f, -1.f);
    float4* a = (float4*)inbm;
    for (unsigned i = tid; i < (8u << 20) / 16u; i += nthr) a[i] = z;
    float4* pb = (float4*)parbm;               // parbm+refbm contiguous 2 MB
    for (unsigned i = tid; i < (2u << 20) / 16u; i += nthr) pb[i] = z;
    float4* of = (float4*)out_feats;
    unsigned n4 = (unsigned)((size_t)N * 65u / 4u);
    for (unsigned i = tid; i < n4; i += nthr) of[i] = z;
    for (unsigned i = tid; i < (unsigned)N; i += nthr) out_coords[i] = m1;
  }
  grid.sync();

  // ---- P1: build all bitmaps ----
  for (unsigned i = tid; i < (unsigned)(N + NREF); i += nthr) {
    if (i < (unsigned)N) {
      int4 c = coords[i];                      // (b,x,y,z)
      unsigned key = key_of(c.x, c.y, c.z, c.w);
      atomicOr(&inbm[key >> 5], 1u << (key & 31));
      unsigned k23 = ((unsigned)c.x << 21) | ((unsigned)(c.y >> 1) << 14) |
                     ((unsigned)(c.z >> 1) << 7) | (unsigned)(c.w >> 1);
      atomicOr(&parbm[k23 >> 5], 1u << (k23 & 31));
    } else {
      int4 c = ref[i - (unsigned)N];           // even coords on stride-2 grid
      unsigned k23 = ((unsigned)c.x << 21) | ((unsigned)(c.y >> 1) << 14) |
                     ((unsigned)(c.z >> 1) << 7) | (unsigned)(c.w >> 1);
      atomicOr(&refbm[k23 >> 5], 1u << (k23 & 31));
    }
  }
  grid.sync();

  // ---- P2: maskbm = parbm & refbm (in place) + per-logical-block popcount sums ----
  for (unsigned blk = blockIdx.x; blk < NBLK; blk += gridDim.x) {
    unsigned base = blk * 1024u + t * 4u;
    unsigned cin = 0;
#pragma unroll
    for (int k = 0; k < 4; k++) cin += __popc(inbm[base + k]);
    unsigned cpar = 0, cmask = 0;
    if (t < 128u) {
      unsigned w = blk * 128u + t;
      unsigned p = parbm[w];
      unsigned m = p & refbm[w];
      refbm[w] = m;                            // refbm becomes maskbm
      cpar = __popc(p);
      cmask = __popc(m);
    }
    s[t] = cin; __syncthreads();
    for (int off = 128; off > 0; off >>= 1) { if (t < (unsigned)off) s[t] += s[t + off]; __syncthreads(); }
    if (t == 0) bsums[blk] = s[0];
    __syncthreads();
    s[t] = cpar; __syncthreads();
    for (int off = 128; off > 0; off >>= 1) { if (t < (unsigned)off) s[t] += s[t + off]; __syncthreads(); }
    if (t == 0) bsums[NBLK + blk] = s[0];
    __syncthreads();
    s[t] = cmask; __syncthreads();
    for (int off = 128; off > 0; off >>= 1) { if (t < (unsigned)off) s[t] += s[t + off]; __syncthreads(); }
    if (t == 0) bsums[2 * NBLK + blk] = s[0];
    __syncthreads();
  }
  grid.sync();

  // ---- P3: scan the 3 block-sum arrays (logical blocks 0..2) ----
  for (unsigned a = blockIdx.x; a < 3u; a += gridDim.x) {
    const unsigned* src = bsums + a * NBLK;
    unsigned* dst = bscan + a * NBLK;
    unsigned loc[8], sum = 0;
#pragma unroll
    for (int k = 0; k < 8; k++) { loc[k] = src[t * 8 + k]; sum += loc[k]; }
    s[t] = sum; __syncthreads();
    for (int off = 1; off < 256; off <<= 1) {
      unsigned v = (t >= (unsigned)off) ? s[t - off] : 0u;
      __syncthreads(); s[t] += v; __syncthreads();
    }
    if (a == 2u && t == 255u) counter[0] = s[255];
    unsigned excl = (t == 0) ? 0u : s[t - 1];
#pragma unroll
    for (int k = 0; k < 8; k++) { dst[t * 8 + k] = excl; excl += loc[k]; }
    __syncthreads();
  }
  grid.sync();

  // ---- P4: per-word exclusive prefixes ----
  for (unsigned blk = blockIdx.x; blk < NBLK; blk += gridDim.x) {
    unsigned base = blk * 1024u + t * 4u;
    unsigned c4[4], sum = 0;
#pragma unroll
    for (int k = 0; k < 4; k++) { c4[k] = __popc(inbm[base + k]); sum += c4[k]; }
    s[t] = sum; __syncthreads();
    for (int off = 1; off < 256; off <<= 1) {
      unsigned v = (t >= (unsigned)off) ? s[t - off] : 0u;
      __syncthreads(); s[t] += v; __syncthreads();
    }
    unsigned excl = ((t == 0) ? 0u : s[t - 1]) + bscan[blk];
#pragma unroll
    for (int k = 0; k < 4; k++) { inpre[base + k] = excl; excl += c4[k]; }
    __syncthreads();

    unsigned w = blk * 128u + t;
    unsigned cp = (t < 128u) ? __popc(parbm[w]) : 0u;
    s[t] = cp; __syncthreads();
    for (int off = 1; off < 256; off <<= 1) {
      unsigned v = (t >= (unsigned)off) ? s[t - off] : 0u;
      __syncthreads(); s[t] += v; __syncthreads();
    }
    if (t < 128u) parpre[w] = ((t == 0) ? 0u : s[t - 1]) + bscan[NBLK + blk];
    __syncthreads();

    unsigned cm = (t < 128u) ? __popc(refbm[w]) : 0u;
    s[t] = cm; __syncthreads();
    for (int off = 1; off < 256; off <<= 1) {
      unsigned v = (t >= (unsigned)off) ? s[t - off] : 0u;
      __syncthreads(); s[t] += v; __syncthreads();
    }
    if (t < 128u) maskpre[w] = ((t == 0) ? 0u : s[t - 1]) + bscan[2 * NBLK + blk];
    __syncthreads();
  }
  grid.sync();

  // ---- P5: srow scatter + emit coords/mask/mlist ----
  for (unsigned i = tid; i < (unsigned)N; i += nthr) {
    int4 c = coords[i];
    unsigned key = key_of(c.x, c.y, c.z, c.w);
    unsigned w = key >> 5, b = key & 31u;
    unsigned r = inpre[w] + __popc(inbm[w] & ((1u << b) - 1u));
    srow[r] = i;
  }
  for (unsigned w = tid; w < WORDS_P; w += nthr) {
    unsigned bits = parbm[w];
    if (!bits) continue;
    unsigned mb = refbm[w];
    unsigned r = parpre[w];
    unsigned j = maskpre[w];
    while (bits) {
      unsigned b = (unsigned)__ffs((int)bits) - 1u;
      bits &= bits - 1u;
      unsigned k23 = (w << 5) | b;
      unsigned bb = k23 >> 21;
      unsigned x = ((k23 >> 14) & 127u) * 2u;
      unsigned y = ((k23 >> 7) & 127u) * 2u;
      unsigned z = (k23 & 127u) * 2u;
      out_coords[r] = make_float4((float)bb, (float)x, (float)y, (float)z);
      if ((mb >> b) & 1u) {
        out_mask[r] = 1.0f;
        mlist[j++] = make_uint2((bb << 24) | (x << 16) | (y << 8) | z, r);
      }
      r++;
    }
  }
  grid.sync();

  // ---- P6: conv on masked rows; one wave per row; lanes 0-7 probe children ----
  {
    unsigned lane = t & 63u;
    unsigned wave = tid >> 6;
    unsigned nwaves = nthr >> 6;
    unsigned M = counter[0];
    float bv = bias[lane];
    for (unsigned j = wave; j < M; j += nwaves) {
      uint2 e = mlist[j];
      unsigned key = e.x, r = e.y;
      unsigned v = 0u;
      if (lane < 8u) {
        unsigned ck = key + ((lane >> 2) << 16) + (((lane >> 1) & 1u) << 8) + (lane & 1u);
        unsigned word = inbm[ck >> 5];
        unsigned bit = ck & 31u;
        if ((word >> bit) & 1u) {
          unsigned rk = inpre[ck >> 5] + __popc(word & ((1u << bit) - 1u));
          v = srow[rk] + 1u;                   // row + 1 (0 = absent)
        }
      }
      float acc = bv;
#pragma unroll
      for (int i = 0; i < 8; i++) {
        unsigned vi = (unsigned)__builtin_amdgcn_readfirstlane(__shfl((int)v, i, 64));
        if (vi) {                              // wave-uniform branch
          const float* f = feats + (size_t)(vi - 1u) * 32u;  // SGPR base
          const float* wl = Wg + i * 2048 + lane;            // L2-resident W
#pragma unroll
          for (int k = 0; k < 32; k++) acc = fmaf(f[k], wl[k * 64], acc);
        }
      }
      out_feats[(size_t)r * 64u + lane] = acc;
    }
  }
}

extern "C" void kernel_launch(void* const* d_in, const int* in_sizes, int n_in,
                              void* d_out, int out_size, void* d_ws, size_t ws_size,
                              hipStream_t stream) {
  const float* feats = (const float*)d_in[0];
  const float* W     = (const float*)d_in[1];
  const float* bias  = (const float*)d_in[2];
  const int4*  coords = (const int4*)d_in[3];
  const int4*  ref    = (const int4*)d_in[4];
  int N    = in_sizes[0] / 32;
  int NREF = in_sizes[4] / 4;
  float* outbuf = (float*)d_out;
  char*  wsc    = (char*)d_ws;

  // cooperative grid: must be fully co-resident. 256 CUs on MI355X.
  int maxBlocksPerCU = 0;
  hipOccupancyMaxActiveBlocksPerMultiprocessor(&maxBlocksPerCU, mega, 256, 0);
  if (maxBlocksPerCU < 1) maxBlocksPerCU = 1;
  long long grid_ll = (long long)maxBlocksPerCU * 256;
  int grid = (grid_ll > 2048) ? 2048 : (int)grid_ll;

  void* args[] = {(void*)&feats, (void*)&W, (void*)&bias, (void*)&coords,
                  (void*)&ref, (void*)&N, (void*)&NREF, (void*)&outbuf, (void*)&wsc};
  hipLaunchCooperativeKernel(mega, dim3(grid), dim3(256), args, 0, stream);
}

// Round 10
// 149.766 us; speedup vs baseline: 8.8402x; 8.8402x over previous
//
#include <hip/hip_runtime.h>

// G=256, B=4. Parent/ref coords are even -> compressed key k23=(b,x/2,y/2,z/2)
// in 2^23 (1 MB bitmap). Monotone bijection => same sorted-unique order as ref.
#define WORDS_P  (1u << 18)   // 2^23 / 32
#define NBLK2    1024         // 1024 blocks * 256 words = WORDS_P

__device__ __forceinline__ unsigned k23_of(int b, int x, int y, int z) {
  return ((unsigned)b << 21) | ((unsigned)(x >> 1) << 14) |
         ((unsigned)(y >> 1) << 7) | (unsigned)(z >> 1);
}

// ---- fused fill: ws[0..15MB)=0 (parbm,refbm,clist), out feats+mask=0, coords=-1 ----
__global__ __launch_bounds__(256) void fill_all(float4* __restrict__ wsz, size_t n4_ws,
                                                float4* __restrict__ ofm, size_t n4_ofm,
                                                float4* __restrict__ oc, size_t n4_oc) {
  size_t stride = (size_t)gridDim.x * 256u;
  size_t i0 = (size_t)blockIdx.x * 256u + threadIdx.x;
  float4 z = make_float4(0.f, 0.f, 0.f, 0.f);
  float4 m1 = make_float4(-1.f, -1.f, -1.f, -1.f);
  for (size_t i = i0; i < n4_ws; i += stride) wsz[i] = z;
  for (size_t i = i0; i < n4_ofm; i += stride) ofm[i] = z;
  for (size_t i = i0; i < n4_oc; i += stride) oc[i] = m1;
}

// ---- build parent + ref bitmaps (block-range partition) ----
__global__ __launch_bounds__(256) void build_bm(const int4* __restrict__ coords, int n,
                                                const int4* __restrict__ ref, int nref,
                                                unsigned* __restrict__ parbm,
                                                unsigned* __restrict__ refbm, int nbN) {
  if ((int)blockIdx.x < nbN) {
    int i = blockIdx.x * 256 + threadIdx.x;
    if (i >= n) return;
    int4 c = coords[i];                     // (b,x,y,z)
    unsigned k = k23_of(c.x, c.y, c.z, c.w);
    atomicOr(&parbm[k >> 5], 1u << (k & 31));
  } else {
    int i = (blockIdx.x - nbN) * 256 + threadIdx.x;
    if (i >= nref) return;
    int4 c = ref[i];                        // even coords on stride-2 grid
    unsigned k = k23_of(c.x, c.y, c.z, c.w);
    atomicOr(&refbm[k >> 5], 1u << (k & 31));
  }
}

// ---- maskbm = parbm & refbm (in place over refbm) + block sums for both ----
__global__ __launch_bounds__(256) void pop2(const unsigned* __restrict__ parbm,
                                            unsigned* __restrict__ refbm,
                                            unsigned* __restrict__ bsums) {
  __shared__ unsigned s[256];
  unsigned t = threadIdx.x;
  unsigned w = blockIdx.x * 256u + t;
  unsigned p = parbm[w];
  unsigned m = p & refbm[w];
  refbm[w] = m;                              // refbm becomes maskbm
  s[t] = __popc(p); __syncthreads();
  for (int off = 128; off > 0; off >>= 1) { if (t < (unsigned)off) s[t] += s[t + off]; __syncthreads(); }
  if (t == 0) bsums[blockIdx.x] = s[0];
  __syncthreads();
  s[t] = __popc(m); __syncthreads();
  for (int off = 128; off > 0; off >>= 1) { if (t < (unsigned)off) s[t] += s[t + off]; __syncthreads(); }
  if (t == 0) bsums[NBLK2 + blockIdx.x] = s[0];
}

// ---- scan the 2 block-sum arrays (one block each); mask block writes total M ----
__global__ __launch_bounds__(256) void scan2(const unsigned* __restrict__ bsums,
                                             unsigned* __restrict__ bscan,
                                             unsigned* __restrict__ counter) {
  __shared__ unsigned s[256];
  unsigned a = blockIdx.x;
  const unsigned* src = bsums + a * NBLK2;
  unsigned* dst = bscan + a * NBLK2;
  unsigned t = threadIdx.x;
  unsigned loc[4], sum = 0;
#pragma unroll
  for (int k = 0; k < 4; k++) { loc[k] = src[t * 4 + k]; sum += loc[k]; }
  s[t] = sum; __syncthreads();
  for (int off = 1; off < 256; off <<= 1) {
    unsigned v = (t >= (unsigned)off) ? s[t - off] : 0u;
    __syncthreads(); s[t] += v; __syncthreads();
  }
  if (a == 1u && t == 255u) counter[0] = s[255];   // total masked parents M
  unsigned excl = (t == 0) ? 0u : s[t - 1];
#pragma unroll
  for (int k = 0; k < 4; k++) { dst[t * 4 + k] = excl; excl += loc[k]; }
}

// ---- per-word exclusive prefixes for parbm and maskbm ----
__global__ __launch_bounds__(256) void prefix2(const unsigned* __restrict__ parbm,
                                               const unsigned* __restrict__ maskbm,
                                               const unsigned* __restrict__ bscan,
                                               unsigned* __restrict__ parpre,
                                               unsigned* __restrict__ maskpre) {
  __shared__ unsigned s[256];
  unsigned t = threadIdx.x;
  unsigned w = blockIdx.x * 256u + t;
  unsigned cp = __popc(parbm[w]);
  s[t] = cp; __syncthreads();
  for (int off = 1; off < 256; off <<= 1) {
    unsigned v = (t >= (unsigned)off) ? s[t - off] : 0u;
    __syncthreads(); s[t] += v; __syncthreads();
  }
  parpre[w] = ((t == 0) ? 0u : s[t - 1]) + bscan[blockIdx.x];
  __syncthreads();
  unsigned cm = __popc(maskbm[w]);
  s[t] = cm; __syncthreads();
  for (int off = 1; off < 256; off <<= 1) {
    unsigned v = (t >= (unsigned)off) ? s[t - off] : 0u;
    __syncthreads(); s[t] += v; __syncthreads();
  }
  maskpre[w] = ((t == 0) ? 0u : s[t - 1]) + bscan[NBLK2 + blockIdx.x];
}

// ---- fused: input->clist scatter (blocks [0,nbN)) + emit (blocks [nbN,nbN+1024)) ----
// clist slot (maskrank*8 + childoff) is UNIQUE per input -> no atomics, deterministic.
__global__ __launch_bounds__(256) void scatter_emit(const int4* __restrict__ coords, int n,
                                                    const unsigned* __restrict__ parbm,
                                                    const unsigned* __restrict__ parpre,
                                                    const unsigned* __restrict__ maskbm,
                                                    const unsigned* __restrict__ maskpre,
                                                    unsigned* __restrict__ clist,
                                                    unsigned* __restrict__ mrow,
                                                    float4* __restrict__ out_coords,
                                                    float* __restrict__ out_mask,
                                                    int nbN) {
  if ((int)blockIdx.x < nbN) {
    int i = blockIdx.x * 256 + threadIdx.x;
    if (i >= n) return;
    int4 c = coords[i];
    unsigned k = k23_of(c.x, c.y, c.z, c.w);
    unsigned w = k >> 5, b = k & 31u;
    unsigned mw = maskbm[w];
    if ((mw >> b) & 1u) {
      unsigned j = maskpre[w] + __popc(mw & ((1u << b) - 1u));
      unsigned off = (((unsigned)c.y & 1u) << 2) | (((unsigned)c.z & 1u) << 1) |
                     ((unsigned)c.w & 1u);
      clist[j * 8u + off] = (unsigned)i + 1u;  // row + 1 (0 = absent)
    }
    return;
  }
  unsigned w = (blockIdx.x - nbN) * 256u + threadIdx.x;
  unsigned bits = parbm[w];
  if (!bits) return;
  unsigned mb = maskbm[w];
  unsigned r = parpre[w];
  unsigned j = maskpre[w];
  while (bits) {
    unsigned b = (unsigned)__ffs((int)bits) - 1u;
    bits &= bits - 1u;
    unsigned k = (w << 5) | b;
    float bb = (float)(k >> 21);
    float x = (float)(((k >> 14) & 127u) << 1);
    float y = (float)(((k >> 7) & 127u) << 1);
    float z = (float)((k & 127u) << 1);
    out_coords[r] = make_float4(bb, x, y, z);
    if ((mb >> b) & 1u) {
      out_mask[r] = 1.0f;
      mrow[j++] = r;
    }
    r++;
  }
}

// ---- conv: W in LDS; one wave per masked parent; children direct from clist ----
// 1024 threads (16 waves), 64 KB LDS -> 2 blocks/CU; min 8 waves/EU.
__global__ __launch_bounds__(1024, 8) void conv_lds(const float* __restrict__ feats,
                                                    const float* __restrict__ Wg,
                                                    const float* __restrict__ bias,
                                                    const unsigned* __restrict__ clist,
                                                    const unsigned* __restrict__ mrow,
                                                    const unsigned* __restrict__ counter,
                                                    float* __restrict__ out_feats) {
  __shared__ float lw[16384];                // all of W: 8*32*64 floats = 64 KB
  for (unsigned t = threadIdx.x; t < 4096u; t += 1024u)
    ((float4*)lw)[t] = ((const float4*)Wg)[t];
  __syncthreads();

  unsigned lane = threadIdx.x & 63u;
  unsigned wave = blockIdx.x * 16u + (threadIdx.x >> 6);
  unsigned nwaves = gridDim.x * 16u;
  unsigned M = counter[0];
  float bv = bias[lane];
  for (unsigned j = wave; j < M; j += nwaves) {
    unsigned r = mrow[j];                    // uniform load -> broadcast
    uint4 c0 = *(const uint4*)(clist + (size_t)j * 8u);
    uint4 c1 = *(const uint4*)(clist + (size_t)j * 8u + 4u);
    unsigned cs[8] = {c0.x, c0.y, c0.z, c0.w, c1.x, c1.y, c1.z, c1.w};
    float acc = bv;
#pragma unroll
    for (int i = 0; i < 8; i++) {
      unsigned v = (unsigned)__builtin_amdgcn_readfirstlane((int)cs[i]);
      if (v) {                               // wave-uniform branch
        const float* f = feats + (size_t)(v - 1u) * 32u;   // SGPR base -> s_load
        const float* wl = lw + i * 2048 + lane;
#pragma unroll
        for (int k = 0; k < 32; k++) acc = fmaf(f[k], wl[k * 64], acc);
      }
    }
    out_feats[(size_t)r * 64u + lane] = acc;
  }
}

extern "C" void kernel_launch(void* const* d_in, const int* in_sizes, int n_in,
                              void* d_out, int out_size, void* d_ws, size_t ws_size,
                              hipStream_t stream) {
  const float* feats = (const float*)d_in[0];
  const float* W     = (const float*)d_in[1];
  const float* bias  = (const float*)d_in[2];
  const int4*  coords = (const int4*)d_in[3];
  const int4*  ref    = (const int4*)d_in[4];
  int N    = in_sizes[0] / 32;
  int NREF = in_sizes[4] / 4;

  float* out_coords = (float*)d_out;
  float* out_feats  = out_coords + (size_t)N * 4;
  float* out_mask   = out_feats + (size_t)N * 64;

  char* ws = (char*)d_ws;
  unsigned* parbm   = (unsigned*)(ws);                    // 1 MB
  unsigned* refbm   = (unsigned*)(ws + (1u << 20));       // 1 MB (becomes maskbm)
  unsigned* maskbm  = refbm;
  unsigned* clist   = (unsigned*)(ws + (2u << 20));       // 13 MB (8*NREF u32 used)
  unsigned* parpre  = (unsigned*)(ws + (15u << 20));      // 1 MB
  unsigned* maskpre = (unsigned*)(ws + (16u << 20));      // 1 MB
  unsigned* mrow    = (unsigned*)(ws + (17u << 20));      // 2 MB (NREF u32 used)
  unsigned* bsums   = (unsigned*)(ws + (19u << 20));            // 2*1024 u32
  unsigned* bscan   = (unsigned*)(ws + (19u << 20) + 16384);    // 2*1024 u32
  unsigned* counter = (unsigned*)(ws + (19u << 20) + 32768);    // 1 u32

  int nbN = (N + 255) / 256;
  int nbR = (NREF + 255) / 256;

  // 1) fill: ws[0..15MB)=0 (parbm+refbm+clist), feats+mask=0, coords=-1
  fill_all<<<2048, 256, 0, stream>>>((float4*)ws, (size_t)(15u << 20) / 16u,
                                     (float4*)out_feats, (size_t)N * 65u * 4u / 16u,
                                     (float4*)out_coords, (size_t)N);
  // 2) bitmaps
  build_bm<<<nbN + nbR, 256, 0, stream>>>(coords, N, ref, NREF, parbm, refbm, nbN);
  // 3-5) rank structures (1 MB maps)
  pop2<<<NBLK2, 256, 0, stream>>>(parbm, refbm, bsums);
  scan2<<<2, 256, 0, stream>>>(bsums, bscan, counter);
  prefix2<<<NBLK2, 256, 0, stream>>>(parbm, maskbm, bscan, parpre, maskpre);
  // 6) input->clist scatter + emit coords/mask/mrow
  scatter_emit<<<nbN + NBLK2, 256, 0, stream>>>(coords, N, parbm, parpre, maskbm,
                                                maskpre, clist, mrow,
                                                (float4*)out_coords, out_mask, nbN);
  // 7) conv
  conv_lds<<<512, 1024, 0, stream>>>(feats, W, bias, clist, mrow, counter, out_feats);
}